// Round 1
// baseline (283.230 us; speedup 1.0000x reference)
//
#include <hip/hip_runtime.h>
#include <hip/hip_bf16.h>
#include <math.h>

// Problem constants
#define NB 64
#define HH 512
#define WW 512
#define KK 31
#define PP 15
#define TH 64
#define TW 64
#define HALO 94           // TH + KK - 1
#define SIN 97            // smem leading stride (odd -> avoids pow2 bank patterns)

// ws layout: acc[0..63] = inter per image, acc[64..127] = union per image
__global__ void zero_acc(float* acc) {
    acc[threadIdx.x] = 0.0f;
}

__global__ __launch_bounds__(256) void dice_tile_kernel(
        const float* __restrict__ pred,
        const float* __restrict__ mask,
        float* __restrict__ acc) {
    const int b  = blockIdx.z;
    const int ty = blockIdx.y;
    const int tx = blockIdx.x;
    const int tid = threadIdx.x;

    __shared__ float sm[HALO * SIN];   // 94 x 97 mask halo (zero padded)
    __shared__ float hb[HALO * TW];    // 94 x 64 horizontally box-summed
    __shared__ float red[8];

    const float* mbase = mask + (size_t)b * HH * WW;
    const float* pbase = pred + (size_t)b * HH * WW;

    const int y0 = ty * TH - PP;
    const int x0 = tx * TW - PP;

    // ---- Load halo (zero outside image) ----
    for (int i = tid; i < HALO * HALO; i += 256) {
        const int r = i / HALO;
        const int c = i - r * HALO;
        const int gy = y0 + r;
        const int gx = x0 + c;
        float v = 0.0f;
        if (gy >= 0 && gy < HH && gx >= 0 && gx < WW)
            v = mbase[gy * WW + gx];
        sm[r * SIN + c] = v;
    }
    __syncthreads();

    // ---- Horizontal 31-wide running box sum: hb[r][c] = sum_j sm[r][c+j] ----
    // 188 tasks: (row, half) with half = 32 output columns
    if (tid < 2 * HALO) {
        const int r  = tid >> 1;
        const int c0 = (tid & 1) * 32;
        const float* row = &sm[r * SIN + c0];
        float s = 0.0f;
        #pragma unroll
        for (int j = 0; j < KK; ++j) s += row[j];
        float* hrow = &hb[r * TW + c0];
        #pragma unroll
        for (int c = 0; c < 32; ++c) {
            hrow[c] = s;
            s += row[c + KK] - row[c];
        }
    }
    __syncthreads();

    // ---- Vertical 31-tall running box sum, fused epilogue ----
    const int c  = tid & 63;        // output column within tile
    const int rg = tid >> 6;        // 0..3 row group of 16 rows
    const int r0 = rg * 16;

    float s = 0.0f;
    #pragma unroll
    for (int j = 0; j < KK; ++j) s += hb[(r0 + j) * TW + c];

    float inter = 0.0f, uni = 0.0f;
    const int gx = tx * TW + c;
    #pragma unroll
    for (int rr = 0; rr < 16; ++rr) {
        const int row = r0 + rr;
        const int gy  = ty * TH + row;
        const float avg = s * (1.0f / (float)(KK * KK));
        const float m   = sm[(row + PP) * SIN + (c + PP)];
        const float w   = 1.0f + 5.0f * fabsf(avg - m);
        const float x   = pbase[gy * WW + gx];
        const float p   = 1.0f / (1.0f + expf(-x));
        inter += p * m * w;
        uni   += (p + m) * w;
        if (rr < 15) s += hb[(row + KK) * TW + c] - hb[row * TW + c];
    }

    // ---- Block reduction: wave shuffle then cross-wave via LDS ----
    #pragma unroll
    for (int off = 32; off > 0; off >>= 1) {
        inter += __shfl_down(inter, off);
        uni   += __shfl_down(uni, off);
    }
    const int wave = tid >> 6;
    const int lane = tid & 63;
    if (lane == 0) { red[wave] = inter; red[4 + wave] = uni; }
    __syncthreads();
    if (tid == 0) {
        const float ti = red[0] + red[1] + red[2] + red[3];
        const float tu = red[4] + red[5] + red[6] + red[7];
        atomicAdd(&acc[b], ti);
        atomicAdd(&acc[NB + b], tu);
    }
}

__global__ void dice_final_kernel(const float* __restrict__ acc,
                                  float* __restrict__ out) {
    const int t = threadIdx.x;  // 64 threads, one per image
    const float inter = acc[t];
    const float uni   = acc[NB + t];
    float wd = 1.0f - (2.0f * inter + 0.5f) / (uni + 0.5f);
    #pragma unroll
    for (int off = 32; off > 0; off >>= 1) wd += __shfl_down(wd, off);
    if (t == 0) out[0] = wd * (1.0f / (float)NB);
}

extern "C" void kernel_launch(void* const* d_in, const int* in_sizes, int n_in,
                              void* d_out, int out_size, void* d_ws, size_t ws_size,
                              hipStream_t stream) {
    const float* pred = (const float*)d_in[0];
    const float* mask = (const float*)d_in[1];
    float* out = (float*)d_out;
    float* acc = (float*)d_ws;   // 128 floats

    zero_acc<<<1, 128, 0, stream>>>(acc);
    dim3 grid(WW / TW, HH / TH, NB);   // 8 x 8 x 64
    dice_tile_kernel<<<grid, 256, 0, stream>>>(pred, mask, acc);
    dice_final_kernel<<<1, 64, 0, stream>>>(acc, out);
}

// Round 2
// 195.797 us; speedup vs baseline: 1.4465x; 1.4465x over previous
//
#include <hip/hip_runtime.h>
#include <hip/hip_bf16.h>
#include <math.h>

#define NB 64
#define HH 512
#define WW 512
#define KK 31
#define PP 15
#define NSTRIP 16
#define SROWS (HH / NSTRIP)   // 32 rows per strip

// ws layout: acc[0..63] = inter per image, acc[64..127] = union per image
__global__ void zero_acc(float* acc) {
    acc[threadIdx.x] = 0.0f;
}

// One block = one (image, 32-row strip). 512 threads, one column each.
// Vertical 31-row box sum kept as a running register sum.
// Horizontal 31-col box sum via prefix scan: hsum[x] = P[x+15] - P[x-16].
__global__ __launch_bounds__(512, 8) void dice_strip_kernel(
        const float* __restrict__ pred,
        const float* __restrict__ mask,
        float* __restrict__ acc) {
    const int strip = blockIdx.x;
    const int b     = blockIdx.y;
    const int x     = threadIdx.x;          // column 0..511
    const int wave  = x >> 6;
    const int lane  = x & 63;

    __shared__ float wtot[8];
    __shared__ float Pbuf[16 + WW + 16];    // [0..15]=0, [16..527]=P[x], [528..543]=P[511]
    __shared__ float red[16];

    const float* mbase = mask + (size_t)b * HH * WW;
    const float* pbase = pred + (size_t)b * HH * WW;
    const int y0 = strip * SROWS;

    if (x < 16) Pbuf[x] = 0.0f;             // left pad, never rewritten

    // Initial vertical window: rows [y0-15, y0+14] clamped to image
    float vsum = 0.0f;
    {
        const int rlo = (y0 - PP < 0) ? 0 : y0 - PP;
        const int rhi = (y0 + PP - 1 > HH - 1) ? HH - 1 : y0 + PP - 1;
        for (int r = rlo; r <= rhi; ++r) vsum += mbase[r * WW + x];
    }

    float inter = 0.0f, uni = 0.0f;

    for (int i = 0; i < SROWS; ++i) {
        const int y  = y0 + i;
        const int ra = y + PP;       // row entering window
        const int rs = y - PP - 1;   // row leaving window
        const float va = (ra < HH) ? mbase[ra * WW + x] : 0.0f;
        const float vs = (rs >= 0) ? mbase[rs * WW + x] : 0.0f;
        vsum += va - vs;

        // --- wave-inclusive scan of vsum over 64 lanes ---
        float incl = vsum;
        #pragma unroll
        for (int off = 1; off < 64; off <<= 1) {
            float t = __shfl_up(incl, off);
            if (lane >= off) incl += t;
        }
        if (lane == 63) wtot[wave] = incl;
        __syncthreads();   // B1: wtot visible

        // base for this wave = sum of wtot[0..wave-1]; butterfly gives it to all lanes
        float bm = (lane < wave) ? wtot[lane] : 0.0f;
        #pragma unroll
        for (int off = 1; off < 64; off <<= 1) bm += __shfl_xor(bm, off);

        const float P = bm + incl;
        Pbuf[16 + x] = P;
        if (wave == 7) {
            // P[511] broadcast within wave 7; lanes 48..63 fill right pad
            const float p511 = bm + __shfl(incl, 63);
            if (lane >= 48) Pbuf[528 + (lane - 48)] = p511;
        }
        __syncthreads();   // B2: Pbuf visible

        const float hsum = Pbuf[16 + x + PP] - Pbuf[x];   // P[min(x+15,511)] - P[x-16]
        const float avg  = hsum * (1.0f / (float)(KK * KK));
        const float m    = mbase[y * WW + x];
        const float w    = 1.0f + 5.0f * fabsf(avg - m);
        const float pr   = pbase[y * WW + x];
        const float sg   = 1.0f / (1.0f + __expf(-pr));
        inter += sg * m * w;
        uni   += (sg + m) * w;
        // next iteration's B1 guarantees all Pbuf reads of this iter are done
        // before anyone rewrites Pbuf/wtot
    }

    // --- block reduction ---
    #pragma unroll
    for (int off = 32; off > 0; off >>= 1) {
        inter += __shfl_down(inter, off);
        uni   += __shfl_down(uni, off);
    }
    if (lane == 0) { red[wave] = inter; red[8 + wave] = uni; }
    __syncthreads();
    if (x == 0) {
        float ti = 0.0f, tu = 0.0f;
        #pragma unroll
        for (int w2 = 0; w2 < 8; ++w2) { ti += red[w2]; tu += red[8 + w2]; }
        atomicAdd(&acc[b], ti);
        atomicAdd(&acc[NB + b], tu);
    }
}

__global__ void dice_final_kernel(const float* __restrict__ acc,
                                  float* __restrict__ out) {
    const int t = threadIdx.x;  // 64 threads, one per image
    const float inter = acc[t];
    const float uni   = acc[NB + t];
    float wd = 1.0f - (2.0f * inter + 0.5f) / (uni + 0.5f);
    #pragma unroll
    for (int off = 32; off > 0; off >>= 1) wd += __shfl_down(wd, off);
    if (t == 0) out[0] = wd * (1.0f / (float)NB);
}

extern "C" void kernel_launch(void* const* d_in, const int* in_sizes, int n_in,
                              void* d_out, int out_size, void* d_ws, size_t ws_size,
                              hipStream_t stream) {
    const float* pred = (const float*)d_in[0];
    const float* mask = (const float*)d_in[1];
    float* out = (float*)d_out;
    float* acc = (float*)d_ws;   // 128 floats

    zero_acc<<<1, 128, 0, stream>>>(acc);
    dim3 grid(NSTRIP, NB);       // 16 strips x 64 images = 1024 blocks
    dice_strip_kernel<<<grid, 512, 0, stream>>>(pred, mask, acc);
    dice_final_kernel<<<1, 64, 0, stream>>>(acc, out);
}

// Round 3
// 180.015 us; speedup vs baseline: 1.5734x; 1.0877x over previous
//
#include <hip/hip_runtime.h>
#include <hip/hip_bf16.h>
#include <math.h>

#define NB 64
#define HH 512
#define WW 512
#define KK 31
#define PP 15
#define NSTRIP 16
#define SROWS (HH / NSTRIP)     // 32 rows per strip
#define RPB 4                   // rows per barrier round
#define NROUND (SROWS / RPB)    // 8 rounds
#define PSTR 544                // Pbuf row stride: 16 pad + 512 + 16 pad

// ws layout: part[0..1023] = per-block inter, part[1024..2047] = per-block union
// block id = b * NSTRIP + strip

__global__ __launch_bounds__(512, 8) void dice_strip_kernel(
        const float* __restrict__ pred,
        const float* __restrict__ mask,
        float* __restrict__ part) {
    const int strip = blockIdx.x;
    const int b     = blockIdx.y;
    const int x     = threadIdx.x;          // column 0..511
    const int wave  = x >> 6;
    const int lane  = x & 63;

    __shared__ float wtot[RPB * 8];
    __shared__ float Pbuf[RPB * PSTR];      // per row: [0..15]=0, [16..527]=P, [528..543]=P[511]
    __shared__ float red[16];

    const float* mbase = mask + (size_t)b * HH * WW;
    const float* pbase = pred + (size_t)b * HH * WW;
    const int y0 = strip * SROWS;

    // left pads (never rewritten)
    if (x < 16) {
        #pragma unroll
        for (int r = 0; r < RPB; ++r) Pbuf[r * PSTR + x] = 0.0f;
    }

    // vcarry = vsum for row y0-1: mask rows [y0-16, y0+14] clamped
    float vcarry = 0.0f;
    {
        const int rlo = (y0 - PP - 1 < 0) ? 0 : y0 - PP - 1;
        const int rhi = (y0 + PP - 1 > HH - 1) ? HH - 1 : y0 + PP - 1;
        for (int r = rlo; r <= rhi; ++r) vcarry += mbase[r * WW + x];
    }

    float inter = 0.0f, uni = 0.0f;

    for (int j = 0; j < NROUND; ++j) {
        const int y = y0 + j * RPB;

        // ---- batch all 16 global loads (independent -> MLP) ----
        float en[RPB], lv[RPB], mc[RPB], pv[RPB];
        #pragma unroll
        for (int r = 0; r < RPB; ++r) {
            const int ra = y + r + PP;        // entering row
            const int rs = y + r - PP - 1;    // leaving row
            en[r] = (ra < HH) ? mbase[ra * WW + x] : 0.0f;
            lv[r] = (rs >= 0) ? mbase[rs * WW + x] : 0.0f;
            mc[r] = mbase[(y + r) * WW + x];
            pv[r] = pbase[(y + r) * WW + x];
        }

        // ---- 4 vertical running sums ----
        float incl[RPB];
        {
            float run = vcarry;
            #pragma unroll
            for (int r = 0; r < RPB; ++r) {
                run += en[r] - lv[r];
                incl[r] = run;                // vsum for row y+r
            }
            vcarry = run;
        }

        // ---- 4 interleaved wave-inclusive scans (ILP 4) ----
        #pragma unroll
        for (int off = 1; off < 64; off <<= 1) {
            float t[RPB];
            #pragma unroll
            for (int r = 0; r < RPB; ++r) t[r] = __shfl_up(incl[r], off);
            #pragma unroll
            for (int r = 0; r < RPB; ++r) if (lane >= off) incl[r] += t[r];
        }

        if (lane == 63) {
            #pragma unroll
            for (int r = 0; r < RPB; ++r) wtot[r * 8 + wave] = incl[r];
        }
        __syncthreads();   // B1: wtot visible; everyone done reading old Pbuf

        // ---- per-wave base via interleaved butterflies ----
        float bm[RPB];
        #pragma unroll
        for (int r = 0; r < RPB; ++r)
            bm[r] = (lane < wave) ? wtot[r * 8 + lane] : 0.0f;
        #pragma unroll
        for (int off = 1; off < 64; off <<= 1) {
            #pragma unroll
            for (int r = 0; r < RPB; ++r) bm[r] += __shfl_xor(bm[r], off);
        }

        #pragma unroll
        for (int r = 0; r < RPB; ++r) Pbuf[r * PSTR + 16 + x] = bm[r] + incl[r];
        if (wave == 7) {
            #pragma unroll
            for (int r = 0; r < RPB; ++r) {
                const float p511 = bm[r] + wtot[r * 8 + 7];  // full row sum
                if (lane >= 48) Pbuf[r * PSTR + 528 + (lane - 48)] = p511;
            }
        }
        __syncthreads();   // B2: Pbuf visible

        // ---- fused epilogue for 4 rows ----
        #pragma unroll
        for (int r = 0; r < RPB; ++r) {
            const float hsum = Pbuf[r * PSTR + 16 + x + PP] - Pbuf[r * PSTR + x];
            const float avg  = hsum * (1.0f / (float)(KK * KK));
            const float m    = mc[r];
            const float w    = 1.0f + 5.0f * fabsf(avg - m);
            const float sg   = 1.0f / (1.0f + __expf(-pv[r]));
            inter += sg * m * w;
            uni   += (sg + m) * w;
        }
    }

    // ---- block reduction -> per-block partials ----
    #pragma unroll
    for (int off = 32; off > 0; off >>= 1) {
        inter += __shfl_down(inter, off);
        uni   += __shfl_down(uni, off);
    }
    if (lane == 0) { red[wave] = inter; red[8 + wave] = uni; }
    __syncthreads();
    if (x == 0) {
        float ti = 0.0f, tu = 0.0f;
        #pragma unroll
        for (int w2 = 0; w2 < 8; ++w2) { ti += red[w2]; tu += red[8 + w2]; }
        const int bid = b * NSTRIP + strip;
        part[bid] = ti;
        part[NB * NSTRIP + bid] = tu;
    }
}

__global__ void dice_final_kernel(const float* __restrict__ part,
                                  float* __restrict__ out) {
    const int t = threadIdx.x;  // 64 threads, one per image
    float inter = 0.0f, uni = 0.0f;
    #pragma unroll
    for (int s = 0; s < NSTRIP; ++s) {
        inter += part[t * NSTRIP + s];
        uni   += part[NB * NSTRIP + t * NSTRIP + s];
    }
    float wd = 1.0f - (2.0f * inter + 0.5f) / (uni + 0.5f);
    #pragma unroll
    for (int off = 32; off > 0; off >>= 1) wd += __shfl_down(wd, off);
    if (t == 0) out[0] = wd * (1.0f / (float)NB);
}

extern "C" void kernel_launch(void* const* d_in, const int* in_sizes, int n_in,
                              void* d_out, int out_size, void* d_ws, size_t ws_size,
                              hipStream_t stream) {
    const float* pred = (const float*)d_in[0];
    const float* mask = (const float*)d_in[1];
    float* out  = (float*)d_out;
    float* part = (float*)d_ws;   // 2048 floats

    dim3 grid(NSTRIP, NB);        // 16 strips x 64 images = 1024 blocks
    dice_strip_kernel<<<grid, 512, 0, stream>>>(pred, mask, part);
    dice_final_kernel<<<1, 64, 0, stream>>>(part, out);
}